// Round 1
// 481.854 us; speedup vs baseline: 1.0037x; 1.0037x over previous
//
#include <hip/hip_runtime.h>
#include <hip/hip_bf16.h>

// Problem constants (from reference)
#define NN 20000
#define EE 320000
#define FF 75
#define GG 64
#define LL 5
#define EPS 1e-5f

// GEMM paddings
#define KUV 96      // K for uv gemm (h: 75 -> 96; col 75 = 1.0 bias trick)
#define NUV 160     // cols: u at 0..74, v at 80..154
#define KPOST 384   // K for post gemm ([h|agg]: 375 -> 384)
#define KLIN 96

typedef short bf16x8 __attribute__((ext_vector_type(8)));
typedef float f32x4 __attribute__((ext_vector_type(4)));

__device__ inline void gAtomicAdd(float* p, float v) { unsafeAtomicAdd(p, v); }

__device__ inline ushort f2bs(float x) {
    __hip_bfloat16 b = __float2bfloat16(x);
    return *(ushort*)&b;
}

__device__ inline float bs2f(ushort u) {
    unsigned int x = ((unsigned int)u) << 16;
    return __uint_as_float(x);
}

// ---------------- CSR construction ----------------

__global__ void count_kernel(const int* __restrict__ col, int* __restrict__ cnt, int E) {
    int e = blockIdx.x * blockDim.x + threadIdx.x;
    if (e < E) atomicAdd(&cnt[col[e]], 1);
}

// dinv + sumlog + per-block cnt sums (merged)
__global__ void dinv_partial_kernel(const int* __restrict__ cnt, float* __restrict__ dinv,
                                    float* __restrict__ scal, int* __restrict__ bsum, int N) {
    __shared__ float red[256];
    __shared__ int redi[256];
    int tid = threadIdx.x;
    int i = blockIdx.x * 256 + tid;
    float lg = 0.f;
    int cv = 0;
    if (i < N) {
        cv = cnt[i];
        float c = (float)cv;
        dinv[i] = 1.f / sqrtf(c + 1.f);
        lg = logf(c + 1.f);
    }
    red[tid] = lg;
    redi[tid] = cv;
    __syncthreads();
    for (int s = 128; s > 0; s >>= 1) {
        if (tid < s) { red[tid] += red[tid + s]; redi[tid] += redi[tid + s]; }
        __syncthreads();
    }
    if (tid == 0) {
        gAtomicAdd(&scal[0], red[0]);
        bsum[blockIdx.x] = redi[0];
    }
}

__global__ void scanb_kernel(const int* __restrict__ bsum, int* __restrict__ bbase,
                             int* __restrict__ offs, int NB) {
    __shared__ int sh[128];
    int tid = threadIdx.x;
    int v = (tid < NB) ? bsum[tid] : 0;
    sh[tid] = v;
    __syncthreads();
    for (int d = 1; d < 128; d <<= 1) {
        int t = (tid >= d) ? sh[tid - d] : 0;
        __syncthreads();
        sh[tid] += t;
        __syncthreads();
    }
    if (tid < NB) bbase[tid] = sh[tid] - v;
    if (tid == 0) offs[NN] = EE;
}

__global__ void offs_kernel(const int* __restrict__ cnt, const int* __restrict__ bbase,
                            int* __restrict__ offs, int* __restrict__ cursor, int N) {
    __shared__ int sh[256];
    int tid = threadIdx.x;
    int i = blockIdx.x * 256 + tid;
    int v = (i < N) ? cnt[i] : 0;
    sh[tid] = v;
    __syncthreads();
    for (int d = 1; d < 256; d <<= 1) {
        int t = (tid >= d) ? sh[tid - d] : 0;
        __syncthreads();
        sh[tid] += t;
        __syncthreads();
    }
    int excl = sh[tid] - v + bbase[blockIdx.x];
    if (i < N) { offs[i] = excl; cursor[i] = excl; }
}

// CSR fill + xs prescale merged: items 0..EE-1 = fill; EE..EE+NN*80-1 = xs
__global__ void fill_xs_kernel(const int* __restrict__ row, const int* __restrict__ col,
                               int* __restrict__ cursor, int* __restrict__ csr,
                               const float* __restrict__ x, const float* __restrict__ gw,
                               const float* __restrict__ dinv, ushort* __restrict__ xs) {
    int idx = blockIdx.x * 256 + threadIdx.x;
    if (idx < EE) {
        int c = col[idx];
        int pos = atomicAdd(&cursor[c], 1);
        csr[pos] = row[idx];
    } else if (idx < EE + NN * 80) {
        int j = idx - EE;
        int n = j / 80, t = j % 80;
        float v = 0.f;
        if (t < FF) {
            float acc = 0.f;
#pragma unroll
            for (int k = 0; k < 6; k++) acc += x[n * 6 + k] * gw[k * FF + t];
            v = dinv[n] * acc;
        }
        xs[j] = f2bs(v);
    }
}

// one wave per node: 6 edge-slots x 10 lanes, bf16x8 (16B) gathers, LDS slot merge
__global__ __launch_bounds__(64) void gcn_kernel(
    const ushort* __restrict__ xs, const float* __restrict__ dinv,
    const int* __restrict__ offs, const int* __restrict__ csr,
    const float* __restrict__ gcn_b, const int* __restrict__ cnt,
    const float* __restrict__ scal, float* __restrict__ o2,
    float* __restrict__ amp, float* __restrict__ att, int N) {
    __shared__ float lred[6][80];
    int i = blockIdx.x;
    int lane = threadIdx.x;
    int s0 = offs[i], s1 = offs[i + 1];
    int s = lane / 10;          // edge slot 0..5 (lanes 0..59)
    int f = lane - s * 10;      // feature-octet 0..9

    if (lane < 60) {
        float a[8];
#pragma unroll
        for (int j = 0; j < 8; j++) a[j] = 0.f;
        int deg = s1 - s0;
        int full = deg / 6;
        int k = s0 + s;
        for (int it = 0; it < full; it++, k += 6) {
            int r = csr[k];
            bf16x8 v = *(const bf16x8*)(xs + (size_t)r * 80 + f * 8);
#pragma unroll
            for (int j = 0; j < 8; j++) a[j] += bs2f((ushort)v[j]);
        }
        if (s < deg - full * 6) {
            int r = csr[k];
            bf16x8 v = *(const bf16x8*)(xs + (size_t)r * 80 + f * 8);
#pragma unroll
            for (int j = 0; j < 8; j++) a[j] += bs2f((ushort)v[j]);
        }
        *(f32x4*)&lred[s][f * 8] = (f32x4){a[0], a[1], a[2], a[3]};
        *(f32x4*)&lred[s][f * 8 + 4] = (f32x4){a[4], a[5], a[6], a[7]};
    }
    __syncthreads();
    if (lane < 40) {
        int t0 = 2 * lane, t1 = t0 + 1;
        float a0 = 0.f, a1 = 0.f;
#pragma unroll
        for (int q = 0; q < 6; q++) {
            float2 p = *(const float2*)&lred[q][t0];
            a0 += p.x;
            a1 += p.y;
        }
        ushort2 vs = *(const ushort2*)(xs + (size_t)i * 80 + t0);
        a0 += bs2f(vs.x);
        a1 += bs2f(vs.y);
        float di = dinv[i];
        if (t0 < FF) o2[(size_t)i * 80 + t0] = di * a0 + gcn_b[t0];
        if (t1 < FF) o2[(size_t)i * 80 + t1] = di * a1 + gcn_b[t1];
    } else if (lane == 63) {
        float al = scal[0] / (float)N;
        float d = fmaxf((float)cnt[i], 1.f);
        float lg = logf(d + 1.f);
        amp[i] = lg / al;
        att[i] = al / lg;
    }
}

// ---------------- B-matrix prep (bf16, transposed: BT[col][k]) ----------------

#define S_UV (LL * NUV * KUV)
#define S_POST (LL * 240 * KPOST)
#define S_LIN (LL * 80 * KLIN)

__global__ void prep_bt_kernel(const float* __restrict__ pre_w, const float* __restrict__ pre_b,
                               const float* __restrict__ post_w, const float* __restrict__ lin_w,
                               ushort* __restrict__ BTuv, ushort* __restrict__ BTpost,
                               ushort* __restrict__ BTlin) {
    int idx = blockIdx.x * 256 + threadIdx.x;
    if (idx < S_UV) {
        int l = idx / (NUV * KUV);
        int r = idx % (NUV * KUV);
        int c = r / KUV, k = r % KUV;
        float v = 0.f;
        if (k < FF) {
            if (c < FF) v = pre_w[((size_t)l * 150 + k) * FF + c];
            else if (c >= 80 && c < 80 + FF) v = pre_w[((size_t)l * 150 + FF + k) * FF + (c - 80)];
        } else if (k == FF && c < FF) {
            v = pre_b[l * FF + c];  // bias fold: A col75 = 1.0
        }
        BTuv[idx] = f2bs(v);
    } else if (idx < S_UV + S_POST) {
        int j = idx - S_UV;
        int l = j / (240 * KPOST);
        int r = j % (240 * KPOST);
        int c = r / KPOST, k = r % KPOST;
        float v = 0.f;
        if (k < FF) {
            if (c < FF) v = post_w[((size_t)l * 975 + k) * FF + c];
        } else if (k < 375) {
            if (c < FF) v = post_w[((size_t)l * 975 + k) * FF + c];
            else if (c >= 80 && c < 80 + FF) v = post_w[((size_t)l * 975 + k + 300) * FF + (c - 80)];
            else if (c >= 160 && c < 160 + FF) v = post_w[((size_t)l * 975 + k + 600) * FF + (c - 160)];
        }
        BTpost[j] = f2bs(v);
    } else if (idx < S_UV + S_POST + S_LIN) {
        int j = idx - S_UV - S_POST;
        int l = j / (80 * KLIN);
        int r = j % (80 * KLIN);
        int c = r / KLIN, k = r % KLIN;
        float v = (c < FF && k < FF) ? lin_w[((size_t)l * FF + k) * FF + c] : 0.f;
        BTlin[j] = f2bs(v);
    }
}

// ---------------- fused BN + uv GEMM (1 wave = 32 rows, B reused across 2 tiles) ----------------

__global__ __launch_bounds__(64) void uv_bn_kernel(
    const float* __restrict__ o2, const float* __restrict__ slots,
    const float* __restrict__ bg, const float* __restrict__ bb, int apply_bn,
    const ushort* __restrict__ BT, float* __restrict__ U, ushort* __restrict__ Vb,
    ushort* __restrict__ hagg) {
    __shared__ float ssL[160];
    int lane = threadIdx.x;
    int col16 = lane & 15, quad = lane >> 4;
    int nA = blockIdx.x * 32 + col16;
    const float* orowA = o2 + (size_t)nA * 80;
    const float* orowB = orowA + 16 * 80;
    const ushort* bbase = BT + (size_t)col16 * KUV + quad * 8;

    if (apply_bn) {
        for (int c = lane; c < 80; c += 64) {
            if (c < FF) {
                float su = 0.f, sq = 0.f;
#pragma unroll 8
                for (int s = 0; s < 32; s++) {
                    su += slots[s * 160 + c];
                    sq += slots[s * 160 + 80 + c];
                }
                float mu = su * (1.f / (float)NN);
                float var = sq * (1.f / (float)NN) - mu * mu;
                float sc = bg[c] * rsqrtf(var + EPS);
                ssL[c] = sc;
                ssL[80 + c] = bb[c] - mu * sc;
            } else {
                ssL[c] = 0.f;
                ssL[80 + c] = 0.f;
            }
        }
        __syncthreads();
    }

    f32x4 accA[10], accB[10];
#pragma unroll
    for (int i = 0; i < 10; i++) {
        accA[i] = (f32x4){0.f, 0.f, 0.f, 0.f};
        accB[i] = (f32x4){0.f, 0.f, 0.f, 0.f};
    }

#pragma unroll
    for (int kt = 0; kt < 3; kt++) {
        int kb = kt * 32 + quad * 8;
        bf16x8 afA, afB;
        if (kb < 80) {
            float4 a0 = *(const float4*)(orowA + kb);
            float4 a1 = *(const float4*)(orowA + kb + 4);
            float4 b0 = *(const float4*)(orowB + kb);
            float4 b1 = *(const float4*)(orowB + kb + 4);
            float vA[8] = {a0.x, a0.y, a0.z, a0.w, a1.x, a1.y, a1.z, a1.w};
            float vB[8] = {b0.x, b0.y, b0.z, b0.w, b1.x, b1.y, b1.z, b1.w};
#pragma unroll
            for (int j = 0; j < 8; j++) {
                int k = kb + j;
                float xA = vA[j], xB = vB[j];
                if (apply_bn) {
                    xA = fmaxf(xA * ssL[k] + ssL[80 + k], 0.f);
                    xB = fmaxf(xB * ssL[k] + ssL[80 + k], 0.f);
                }
                ushort hA = (k < FF) ? f2bs(xA) : (k == FF ? (ushort)0x3F80 : (ushort)0);
                ushort hB = (k < FF) ? f2bs(xB) : (k == FF ? (ushort)0x3F80 : (ushort)0);
                afA[j] = (short)hA;
                afB[j] = (short)hB;
            }
            if (kb < FF) {
                // h-cols of hagg; forced values at cols 75..79 are overwritten by edge_agg
                *(bf16x8*)(hagg + (size_t)nA * KPOST + kb) = afA;
                *(bf16x8*)(hagg + (size_t)(nA + 16) * KPOST + kb) = afB;
            }
        } else {
            afA = (bf16x8){0, 0, 0, 0, 0, 0, 0, 0};
            afB = (bf16x8){0, 0, 0, 0, 0, 0, 0, 0};
        }
#pragma unroll
        for (int nt = 0; nt < 10; nt++) {
            bf16x8 bfr = *(const bf16x8*)(bbase + nt * (16 * KUV) + kt * 32);
            accA[nt] = __builtin_amdgcn_mfma_f32_16x16x32_bf16(afA, bfr, accA[nt], 0, 0, 0);
            accB[nt] = __builtin_amdgcn_mfma_f32_16x16x32_bf16(afB, bfr, accB[nt], 0, 0, 0);
        }
    }
    int n0 = blockIdx.x * 32;
#pragma unroll
    for (int nt = 0; nt < 10; nt++) {
        int col = nt * 16 + col16;
#pragma unroll
        for (int r = 0; r < 4; r++) {
            int nnA = n0 + quad * 4 + r;
            int nnB = nnA + 16;
            if (col < FF) {
                U[(size_t)nnA * 80 + col] = accA[nt][r];
                U[(size_t)nnB * 80 + col] = accB[nt][r];
            } else if (col >= 80 && col < 80 + FF) {
                Vb[(size_t)nnA * 80 + (col - 80)] = f2bs(accA[nt][r]);
                Vb[(size_t)nnB * 80 + (col - 80)] = f2bs(accB[nt][r]);
            }
        }
    }
}

// ---------------- fused post GEMM + combine + lin GEMM + BN stats (1 wave = 32 rows) ----------------

__global__ __launch_bounds__(64) void post_lin_kernel(
    const ushort* __restrict__ A, const ushort* __restrict__ BT,
    const ushort* __restrict__ BL, const float* __restrict__ amp,
    const float* __restrict__ att, float* __restrict__ o2,
    float* __restrict__ slots) {
    __shared__ __align__(16) ushort olds[32 * 104];
    int lane = threadIdx.x;
    int col16 = lane & 15, quad = lane >> 4, kseg = quad * 8;
    int n0 = blockIdx.x * 32;
    const ushort* arowA = A + (size_t)(n0 + col16) * KPOST + kseg;
    const ushort* arowB = arowA + (size_t)16 * KPOST;
    const ushort* bbase = BT + (size_t)col16 * KPOST + kseg;

    f32x4 accA[15], accB[15];
#pragma unroll
    for (int i = 0; i < 15; i++) {
        accA[i] = (f32x4){0.f, 0.f, 0.f, 0.f};
        accB[i] = (f32x4){0.f, 0.f, 0.f, 0.f};
    }

#pragma unroll 2
    for (int kt = 0; kt < 12; kt++) {
        bf16x8 afA = *(const bf16x8*)(arowA + kt * 32);
        bf16x8 afB = *(const bf16x8*)(arowB + kt * 32);
#pragma unroll
        for (int nt = 0; nt < 15; nt++) {
            bf16x8 bfr = *(const bf16x8*)(bbase + (size_t)nt * (16 * KPOST) + kt * 32);
            accA[nt] = __builtin_amdgcn_mfma_f32_16x16x32_bf16(afA, bfr, accA[nt], 0, 0, 0);
            accB[nt] = __builtin_amdgcn_mfma_f32_16x16x32_bf16(afB, bfr, accB[nt], 0, 0, 0);
        }
    }
    // combine with amp/att -> o (bf16) in LDS, A-fragment layout
    float ampA[4], attA[4], ampB[4], attB[4];
#pragma unroll
    for (int r = 0; r < 4; r++) {
        int n = n0 + quad * 4 + r;
        ampA[r] = amp[n];
        attA[r] = att[n];
        ampB[r] = amp[n + 16];
        attB[r] = att[n + 16];
    }
#pragma unroll
    for (int g = 0; g < 5; g++) {
        int col = g * 16 + col16;
#pragma unroll
        for (int r = 0; r < 4; r++) {
            float ovA = accA[g][r] + ampA[r] * accA[g + 5][r] + attA[r] * accA[g + 10][r];
            float ovB = accB[g][r] + ampB[r] * accB[g + 5][r] + attB[r] * accB[g + 10][r];
            olds[(quad * 4 + r) * 104 + col] = (col < FF) ? f2bs(ovA) : (ushort)0;
            olds[(16 + quad * 4 + r) * 104 + col] = (col < FF) ? f2bs(ovB) : (ushort)0;
        }
    }
    // zero K-pad cols 80..95 for all 32 rows
    {
        int rr = lane >> 1, cc = 80 + (lane & 1) * 8;
        *(bf16x8*)(olds + rr * 104 + cc) = (bf16x8){0, 0, 0, 0, 0, 0, 0, 0};
    }
    __syncthreads();

    // lin GEMM (K=96)
    f32x4 acc2A[5], acc2B[5];
#pragma unroll
    for (int i = 0; i < 5; i++) {
        acc2A[i] = (f32x4){0.f, 0.f, 0.f, 0.f};
        acc2B[i] = (f32x4){0.f, 0.f, 0.f, 0.f};
    }
    const ushort* blbase = BL + (size_t)col16 * KLIN + kseg;
#pragma unroll
    for (int kt = 0; kt < 3; kt++) {
        bf16x8 afA = *(const bf16x8*)(olds + col16 * 104 + kt * 32 + kseg);
        bf16x8 afB = *(const bf16x8*)(olds + (16 + col16) * 104 + kt * 32 + kseg);
#pragma unroll
        for (int nt = 0; nt < 5; nt++) {
            bf16x8 bfr = *(const bf16x8*)(blbase + nt * (16 * KLIN) + kt * 32);
            acc2A[nt] = __builtin_amdgcn_mfma_f32_16x16x32_bf16(afA, bfr, acc2A[nt], 0, 0, 0);
            acc2B[nt] = __builtin_amdgcn_mfma_f32_16x16x32_bf16(afB, bfr, acc2B[nt], 0, 0, 0);
        }
    }
    // epilogue: store o2 + BN partial sums (fan into 32 slots)
    float* slot = slots + (blockIdx.x & 31) * 160;
#pragma unroll
    for (int nt = 0; nt < 5; nt++) {
        int col = nt * 16 + col16;
        float s = 0.f, q = 0.f;
#pragma unroll
        for (int r = 0; r < 4; r++) {
            int nA = n0 + quad * 4 + r;
            float vA = acc2A[nt][r];
            float vB = acc2B[nt][r];
            if (col < FF) {
                o2[(size_t)nA * 80 + col] = vA;
                o2[(size_t)(nA + 16) * 80 + col] = vB;
                s += vA + vB;
                q += vA * vA + vB * vB;
            }
        }
        s += __shfl_xor(s, 16); s += __shfl_xor(s, 32);
        q += __shfl_xor(q, 16); q += __shfl_xor(q, 32);
        if (lane < 16 && col < FF) {
            gAtomicAdd(&slot[col], s);
            gAtomicAdd(&slot[80 + col], q);
        }
    }
}

// ---------------- edge aggregation: 6 edge-slots x 10 lanes, bf16x8 gathers, LDS merge ----------------

__global__ __launch_bounds__(64) void edge_agg_kernel(
    const float* __restrict__ U, const ushort* __restrict__ V,
    const int* __restrict__ offs, const int* __restrict__ csr,
    const int* __restrict__ cnt, ushort* __restrict__ hagg) {
    __shared__ float lsa[6][80], lsq[6][80], lmn[6][80], lmx[6][80];
    int i = blockIdx.x;
    int lane = threadIdx.x;
    int s0 = offs[i], s1 = offs[i + 1];
    int s = lane / 10;          // edge slot 0..5 (lanes 0..59)
    int f = lane - s * 10;      // feature-octet 0..9

    if (lane < 60) {
        float u[8];
        {
            const float* up = U + (size_t)i * 80 + f * 8;
            float4 u0 = *(const float4*)up;
            float4 u1 = *(const float4*)(up + 4);
            u[0] = u0.x; u[1] = u0.y; u[2] = u0.z; u[3] = u0.w;
            u[4] = u1.x; u[5] = u1.y; u[6] = u1.z; u[7] = u1.w;
        }
        float sa[8], sq[8], mn[8], mx[8];
#pragma unroll
        for (int j = 0; j < 8; j++) {
            sa[j] = 0.f; sq[j] = 0.f; mn[j] = 1e30f; mx[j] = -1e30f;
        }
        int deg = s1 - s0;
        int full = deg / 6;
        int k = s0 + s;
        for (int it = 0; it < full; it++, k += 6) {
            int r = csr[k];
            bf16x8 v = *(const bf16x8*)(V + (size_t)r * 80 + f * 8);
#pragma unroll
            for (int j = 0; j < 8; j++) {
                float av = u[j] + bs2f((ushort)v[j]);
                sa[j] += av;
                sq[j] += av * av;
                mn[j] = fminf(mn[j], av);
                mx[j] = fmaxf(mx[j], av);
            }
        }
        if (s < deg - full * 6) {
            int r = csr[k];
            bf16x8 v = *(const bf16x8*)(V + (size_t)r * 80 + f * 8);
#pragma unroll
            for (int j = 0; j < 8; j++) {
                float av = u[j] + bs2f((ushort)v[j]);
                sa[j] += av;
                sq[j] += av * av;
                mn[j] = fminf(mn[j], av);
                mx[j] = fmaxf(mx[j], av);
            }
        }
        *(f32x4*)&lsa[s][f * 8] = (f32x4){sa[0], sa[1], sa[2], sa[3]};
        *(f32x4*)&lsa[s][f * 8 + 4] = (f32x4){sa[4], sa[5], sa[6], sa[7]};
        *(f32x4*)&lsq[s][f * 8] = (f32x4){sq[0], sq[1], sq[2], sq[3]};
        *(f32x4*)&lsq[s][f * 8 + 4] = (f32x4){sq[4], sq[5], sq[6], sq[7]};
        *(f32x4*)&lmn[s][f * 8] = (f32x4){mn[0], mn[1], mn[2], mn[3]};
        *(f32x4*)&lmn[s][f * 8 + 4] = (f32x4){mn[4], mn[5], mn[6], mn[7]};
        *(f32x4*)&lmx[s][f * 8] = (f32x4){mx[0], mx[1], mx[2], mx[3]};
        *(f32x4*)&lmx[s][f * 8 + 4] = (f32x4){mx[4], mx[5], mx[6], mx[7]};
    }
    __syncthreads();
    if (lane < 40) {
        int t0 = 2 * lane, t1 = t0 + 1;
        float sa0 = 0.f, sq0 = 0.f, mn0 = 1e30f, mx0 = -1e30f;
        float sa1 = 0.f, sq1 = 0.f, mn1 = 1e30f, mx1 = -1e30f;
#pragma unroll
        for (int q = 0; q < 6; q++) {
            float2 pa = *(const float2*)&lsa[q][t0];
            float2 pq = *(const float2*)&lsq[q][t0];
            float2 pn = *(const float2*)&lmn[q][t0];
            float2 px = *(const float2*)&lmx[q][t0];
            sa0 += pa.x; sa1 += pa.y;
            sq0 += pq.x; sq1 += pq.y;
            mn0 = fminf(mn0, pn.x); mn1 = fminf(mn1, pn.y);
            mx0 = fmaxf(mx0, px.x); mx1 = fmaxf(mx1, px.y);
        }
        int c = cnt[i];
        float cc = fmaxf((float)c, 1.f);
        ushort* a = hagg + (size_t)i * KPOST + FF;
        {
            float mean = sa0 / cc;
            float stdv = sqrtf(fmaxf(sq0 / cc - mean * mean, 0.f) + EPS);
            if (c == 0) { mn0 = 0.f; mx0 = 0.f; }
            if (t0 < FF) {
                a[t0] = f2bs(mean);
                a[FF + t0] = f2bs(mn0);
                a[2 * FF + t0] = f2bs(mx0);
                a[3 * FF + t0] = f2bs(stdv);
            }
        }
        {
            float mean = sa1 / cc;
            float stdv = sqrtf(fmaxf(sq1 / cc - mean * mean, 0.f) + EPS);
            if (c == 0) { mn1 = 0.f; mx1 = 0.f; }
            if (t1 < FF) {
                a[t1] = f2bs(mean);
                a[FF + t1] = f2bs(mn1);
                a[2 * FF + t1] = f2bs(mx1);
                a[3 * FF + t1] = f2bs(stdv);
            }
        }
    } else if (lane >= 48 && lane < 57) {
        hagg[(size_t)i * KPOST + 375 + (lane - 48)] = 0;  // K-pad
    }
}

// ---------------- pooling (BN inline, slot reduce per block) + final MLP ----------------

__global__ void pool_kernel(const float* __restrict__ o2, const float* __restrict__ slots,
                            const float* __restrict__ bg, const float* __restrict__ bb,
                            const int* __restrict__ batch, float* __restrict__ g, int N) {
    __shared__ float acc[GG * FF];
    __shared__ float ssL[160];
    int tid = threadIdx.x;
    int n0 = blockIdx.x * 64;
    int n1 = min(n0 + 64, N);
    if (n0 >= N) return;
    for (int c = tid; c < 80; c += 256) {
        if (c < FF) {
            float su = 0.f, sq = 0.f;
#pragma unroll 8
            for (int s = 0; s < 32; s++) {
                su += slots[s * 160 + c];
                sq += slots[s * 160 + 80 + c];
            }
            float mu = su * (1.f / (float)NN);
            float var = sq * (1.f / (float)NN) - mu * mu;
            float sc = bg[c] * rsqrtf(var + EPS);
            ssL[c] = sc;
            ssL[80 + c] = bb[c] - mu * sc;
        } else {
            ssL[c] = 0.f;
            ssL[80 + c] = 0.f;
        }
    }
    int g0 = batch[n0];
    int g1 = batch[n1 - 1];
    int range = g1 - g0 + 1;
    for (int i = tid; i < range * FF; i += 256) acc[i] = 0.f;
    __syncthreads();
    int rows = n1 - n0;
    for (int idx = tid; idx < rows * FF; idx += 256) {
        int r = idx / FF, c = idx % FF;
        int n = n0 + r;
        float val = fmaxf(o2[(size_t)n * 80 + c] * ssL[c] + ssL[80 + c], 0.f);
        gAtomicAdd(&acc[(batch[n] - g0) * FF + c], val);
    }
    __syncthreads();
    for (int i = tid; i < range * FF; i += 256) gAtomicAdd(&g[g0 * FF + i], acc[i]);
}

__global__ void mlp_kernel(const float* __restrict__ g,
                           const float* __restrict__ w1, const float* __restrict__ b1,
                           const float* __restrict__ w2, const float* __restrict__ b2,
                           const float* __restrict__ w3, const float* __restrict__ b3,
                           float* __restrict__ out) {
    __shared__ float gr[FF], h1[50], h2[25];
    int gi = blockIdx.x, t = threadIdx.x;
    for (int j = t; j < FF; j += 64) gr[j] = g[gi * FF + j];
    __syncthreads();
    if (t < 50) {
        float a = b1[t];
        for (int k = 0; k < FF; k++) a += gr[k] * w1[k * 50 + t];
        h1[t] = fmaxf(a, 0.f);
    }
    __syncthreads();
    if (t < 25) {
        float a = b2[t];
        for (int k = 0; k < 50; k++) a += h1[k] * w2[k * 25 + t];
        h2[t] = fmaxf(a, 0.f);
    }
    __syncthreads();
    if (t < 10) {
        float a = b3[t];
        for (int k = 0; k < 25; k++) a += h2[k] * w3[k * 10 + t];
        out[gi * 10 + t] = a;
    }
}

// ---------------- launch ----------------

extern "C" void kernel_launch(void* const* d_in, const int* in_sizes, int n_in,
                              void* d_out, int out_size, void* d_ws, size_t ws_size,
                              hipStream_t stream) {
    const float* x = (const float*)d_in[0];
    const int* ei = (const int*)d_in[1];
    const int* batch = (const int*)d_in[2];
    const float* gcn_w = (const float*)d_in[3];
    const float* gcn_b = (const float*)d_in[4];
    const float* pre_w = (const float*)d_in[5];
    const float* pre_b = (const float*)d_in[6];
    const float* post_w = (const float*)d_in[7];
    const float* lin_w = (const float*)d_in[9];
    const float* bn_g = (const float*)d_in[11];
    const float* bn_b = (const float*)d_in[12];
    const float* w1 = (const float*)d_in[13];
    const float* b1 = (const float*)d_in[14];
    const float* w2 = (const float*)d_in[15];
    const float* b2 = (const float*)d_in[16];
    const float* w3 = (const float*)d_in[17];
    const float* b3 = (const float*)d_in[18];
    float* out = (float*)d_out;

    const int* row = ei;
    const int* col = ei + EE;

    char* ws = (char*)d_ws;
    size_t off = 0;
    auto alloc = [&](size_t bytes) {
        char* p = ws + off;
        off += (bytes + 255) & ~(size_t)255;
        return p;
    };
    // zero-region: cnt + scal + gbuf adjacent, single memset
    size_t z0 = off;
    int* cnt = (int*)alloc(NN * 4);
    float* scal = (float*)alloc((1 + LL * 32 * 160) * 4);  // [0]=sumlog; slots[5][32][160]
    float* gbuf = (float*)alloc(GG * FF * 4);
    size_t z1 = off;
    float* slotbase = scal + 1;
    int* offs = (int*)alloc((NN + 1) * 4);
    int* cursor = (int*)alloc(NN * 4);
    int* csr = (int*)alloc(EE * 4);
    int* bsum = (int*)alloc(128 * 4);
    int* bbase = (int*)alloc(128 * 4);
    float* dinv = (float*)alloc(NN * 4);
    float* amp = (float*)alloc(NN * 4);
    float* att = (float*)alloc(NN * 4);
    float* o2 = (float*)alloc((size_t)NN * 80 * 4);
    float* ubuf = (float*)alloc((size_t)NN * 80 * 4);
    ushort* vbuf = (ushort*)alloc((size_t)NN * 80 * 2);  // xs in setup, V in layers
    ushort* hagg = (ushort*)alloc((size_t)NN * KPOST * 2);
    ushort* BTuv = (ushort*)alloc((size_t)S_UV * 2);
    ushort* BTpost = (ushort*)alloc((size_t)S_POST * 2);
    ushort* BTlin = (ushort*)alloc((size_t)S_LIN * 2);

    hipMemsetAsync(ws + z0, 0, z1 - z0, stream);

    const int B = 256;
    const int NB = (NN + 255) / 256;  // 79
    count_kernel<<<(EE + B - 1) / B, B, 0, stream>>>(col, cnt, EE);
    dinv_partial_kernel<<<NB, B, 0, stream>>>(cnt, dinv, scal, bsum, NN);
    scanb_kernel<<<1, 128, 0, stream>>>(bsum, bbase, offs, NB);
    offs_kernel<<<NB, B, 0, stream>>>(cnt, bbase, offs, cursor, NN);
    fill_xs_kernel<<<(EE + NN * 80 + B - 1) / B, B, 0, stream>>>(row, col, cursor, csr,
                                                                 x, gcn_w, dinv, vbuf);
    gcn_kernel<<<NN, 64, 0, stream>>>(vbuf, dinv, offs, csr, gcn_b, cnt, scal,
                                      o2, amp, att, NN);
    {
        int tot = S_UV + S_POST + S_LIN;
        prep_bt_kernel<<<(tot + B - 1) / B, B, 0, stream>>>(pre_w, pre_b, post_w, lin_w,
                                                            BTuv, BTpost, BTlin);
    }

    const int GS2 = NN / 32;  // 625 single-wave blocks, 32 rows each (exact)
    for (int l = 0; l < LL; l++) {
        float* slots_prev = slotbase + (l - 1) * 32 * 160;  // unused when l==0
        float* slots = slotbase + l * 32 * 160;
        int lp = (l > 0) ? (l - 1) : 0;
        int ab = (l > 0) ? 1 : 0;
        const float* sp = (l == 0) ? slotbase : slots_prev;

        uv_bn_kernel<<<GS2, 64, 0, stream>>>(o2, sp, bn_g + lp * FF, bn_b + lp * FF, ab,
                                             BTuv + (size_t)l * NUV * KUV, ubuf, vbuf, hagg);
        edge_agg_kernel<<<NN, 64, 0, stream>>>(ubuf, vbuf, offs, csr, cnt, hagg);
        post_lin_kernel<<<GS2, 64, 0, stream>>>(hagg, BTpost + (size_t)l * 240 * KPOST,
                                                BTlin + (size_t)l * 80 * KLIN, amp, att,
                                                o2, slots);
    }

    pool_kernel<<<(NN + 63) / 64, 256, 0, stream>>>(o2, slotbase + (LL - 1) * 32 * 160,
                                                    bn_g + (LL - 1) * FF, bn_b + (LL - 1) * FF,
                                                    batch, gbuf, NN);
    mlp_kernel<<<GG, 64, 0, stream>>>(gbuf, w1, b1, w2, b2, w3, b3, out);
}